// Round 2
// baseline (3075.196 us; speedup 1.0000x reference)
//
#include <hip/hip_runtime.h>
#include <hip/hip_bf16.h>

#define B_  64
#define T_  512
#define V_  512
#define E_  128
#define D_  256
#define D2_ 512

typedef unsigned short u16;
typedef unsigned int   u32;
typedef short s16x8 __attribute__((ext_vector_type(8)));
typedef float f32x4 __attribute__((ext_vector_type(4)));
typedef unsigned short u16x2 __attribute__((ext_vector_type(2)));

__device__ __forceinline__ float bf2f(u16 u){
    union { u32 i; float f; } c; c.i = ((u32)u) << 16; return c.f;
}
__device__ __forceinline__ u16 f2bf(float f){
    union { float f; u32 i; } c; c.f = f;
    u32 u = c.i;
    return (u16)((u + 0x7fffu + ((u >> 16) & 1u)) >> 16);
}
__device__ __forceinline__ float tanh_fast(float x){
    float a = fminf(fabsf(x), 15.0f);
    float e = __expf(2.0f * a);
    float r = (e - 1.0f) * __builtin_amdgcn_rcpf(e + 1.0f);
    return copysignf(r, x);
}

// ---------------------------------------------------------------------------
// K1: EW[v,d] = sum_e embed[v,e] * W_ih[e,d] + b_h[d]   (512 x 256, fp32 exact)
// ---------------------------------------------------------------------------
__global__ __launch_bounds__(256) void k_ew(const float* __restrict__ embed,
                                            const float* __restrict__ W_ih,
                                            const float* __restrict__ b_h,
                                            float* __restrict__ EW){
    __shared__ float er[E_];
    int v = blockIdx.x;
    int tid = threadIdx.x;
    if (tid < E_) er[tid] = embed[v*E_ + tid];
    __syncthreads();
    float acc = b_h[tid];
    #pragma unroll 4
    for (int e = 0; e < E_; ++e) acc += er[e] * W_ih[e*D_ + tid];
    EW[v*D_ + tid] = acc;
}

// ---------------------------------------------------------------------------
// K2: sequential h-chain. 4 blocks x 16 batches, 512 threads (8 waves).
// h and W_hh both kept as bf16 hi+lo splits => ~fp32-accurate recurrence:
//   h*W ~= h_hi*W_hi + h_lo*W_hi + h_hi*W_lo   (3 MFMA passes)
// Writes h (bf16) into HC[t*B+b][0:256].
// ---------------------------------------------------------------------------
__global__ __launch_bounds__(512, 2) void k_rnn(const int* __restrict__ x,
                                                const float* __restrict__ EW,
                                                const float* __restrict__ W_hh,
                                                u16* __restrict__ HC){
    __shared__ u16 hhi[16][264];   // 256 + 8 pad
    __shared__ u16 hlo[16][264];
    int tid  = threadIdx.x;
    int lane = tid & 63;
    int w    = tid >> 6;          // wave id 0..7: n-range w*32..w*32+31
    int col  = lane & 15;
    int quad = lane >> 4;
    int bb0  = blockIdx.x * 16;

    // Preload W_hh B-fragments (hi+lo): k = ks*32+quad*8+j, n = w*32+nt*16+col
    s16x8 bfh[2][8], bfl[2][8];
    #pragma unroll
    for (int nt = 0; nt < 2; ++nt){
        int n = w*32 + nt*16 + col;
        #pragma unroll
        for (int ks = 0; ks < 8; ++ks){
            s16x8 th, tl;
            #pragma unroll
            for (int j = 0; j < 8; ++j){
                int k = ks*32 + quad*8 + j;
                float wv = W_hh[k*D_ + n];
                u16 hi = f2bf(wv);
                u16 lo = f2bf(wv - bf2f(hi));
                th[j] = (short)hi;
                tl[j] = (short)lo;
            }
            bfh[nt][ks] = th;
            bfl[nt][ks] = tl;
        }
    }
    for (int i = tid; i < 16*264; i += 512){ (&hhi[0][0])[i] = 0; (&hlo[0][0])[i] = 0; }
    __syncthreads();

    int xr[4];
    float ewv[2][4];
    {   // prefetch xp for t=0
        #pragma unroll
        for (int r = 0; r < 4; ++r) xr[r] = x[(bb0 + quad*4 + r)*T_ + 0];
        #pragma unroll
        for (int nt = 0; nt < 2; ++nt)
            #pragma unroll
            for (int r = 0; r < 4; ++r)
                ewv[nt][r] = EW[xr[r]*D_ + w*32 + nt*16 + col];
    }

    for (int t = 0; t < T_; ++t){
        f32x4 acc[2];
        #pragma unroll
        for (int nt = 0; nt < 2; ++nt)
            #pragma unroll
            for (int r = 0; r < 4; ++r) acc[nt][r] = ewv[nt][r];

        // prefetch next step's xp (overlaps MFMA)
        if (t + 1 < T_){
            #pragma unroll
            for (int r = 0; r < 4; ++r) xr[r] = x[(bb0 + quad*4 + r)*T_ + t + 1];
            #pragma unroll
            for (int nt = 0; nt < 2; ++nt)
                #pragma unroll
                for (int r = 0; r < 4; ++r)
                    ewv[nt][r] = EW[xr[r]*D_ + w*32 + nt*16 + col];
        }

        // MFMA over h_{t-1} (A from LDS, per-ks to bound registers)
        #pragma unroll
        for (int ks = 0; ks < 8; ++ks){
            s16x8 a_hi = *(const s16x8*)&hhi[col][ks*32 + quad*8];
            s16x8 a_lo = *(const s16x8*)&hlo[col][ks*32 + quad*8];
            #pragma unroll
            for (int nt = 0; nt < 2; ++nt){
                acc[nt] = __builtin_amdgcn_mfma_f32_16x16x32_bf16(a_hi, bfh[nt][ks], acc[nt], 0, 0, 0);
                acc[nt] = __builtin_amdgcn_mfma_f32_16x16x32_bf16(a_lo, bfh[nt][ks], acc[nt], 0, 0, 0);
                acc[nt] = __builtin_amdgcn_mfma_f32_16x16x32_bf16(a_hi, bfl[nt][ks], acc[nt], 0, 0, 0);
            }
        }
        __syncthreads();   // all waves done reading h_{t-1} LDS

        // tanh, split hi/lo, write LDS + global
        #pragma unroll
        for (int nt = 0; nt < 2; ++nt){
            #pragma unroll
            for (int r = 0; r < 4; ++r){
                float h  = tanh_fast(acc[nt][r]);
                u16 hi   = f2bf(h);
                u16 lo   = f2bf(h - bf2f(hi));
                int row  = quad*4 + r;
                int n    = w*32 + nt*16 + col;
                hhi[row][n] = hi;
                hlo[row][n] = lo;
                HC[(size_t)(t*B_ + bb0 + row)*D2_ + n] = hi;
            }
        }
        __syncthreads();   // h_t visible for next step
    }
}

// ---------------------------------------------------------------------------
// Generic MFMA GEMM: out[M=32768, N] = A[M, K] (bf16, lda) @ W[K, N] (fp32,
// cast to bf16 at staging) (+bias fp32).
// remap==0: out is bf16, row-major [M, N].
// remap==1: out is fp32; row m = t*64+b is written to out[(b*512 + t)*V + n].
// ---------------------------------------------------------------------------
__global__ __launch_bounds__(256) void k_gemm(const u16* __restrict__ A, int lda,
                                              const float* __restrict__ W,
                                              const float* __restrict__ bias,
                                              void* __restrict__ out,
                                              int K, int N, int remap){
    __shared__ u16 As[64][72];   // [m][k], pad to 72
    __shared__ u16 Ws[64][72];   // [n][k] (transposed), pad to 72
    int tid  = threadIdx.x;
    int lane = tid & 63;
    int w    = tid >> 6;
    int col  = lane & 15;
    int quad = lane >> 4;
    int m0   = blockIdx.x * 64;
    int n0   = blockIdx.y * 64;

    f32x4 acc[4];
    #pragma unroll
    for (int nt = 0; nt < 4; ++nt)
        #pragma unroll
        for (int r = 0; r < 4; ++r) acc[nt][r] = 0.0f;

    for (int kk = 0; kk < K; kk += 64){
        #pragma unroll
        for (int i = 0; i < 8; ++i){           // stage A 64x64 (ushort2)
            int idx = tid + i*256;             // pair index 0..2047
            int r   = idx >> 5;
            int c2  = (idx & 31) * 2;
            u16x2 v2 = *(const u16x2*)&A[(size_t)(m0 + r)*lda + kk + c2];
            *(u16x2*)&As[r][c2] = v2;
        }
        #pragma unroll
        for (int i = 0; i < 16; ++i){          // stage W (fp32 -> bf16), transposed
            int idx = tid + i*256;             // 0..4095
            int k   = idx >> 6;                // 0..63
            int n   = idx & 63;                // 0..63
            Ws[n][k] = f2bf(W[(size_t)(kk + k)*N + n0 + n]);
        }
        __syncthreads();
        #pragma unroll
        for (int ks = 0; ks < 2; ++ks){
            s16x8 a = *(const s16x8*)&As[w*16 + col][ks*32 + quad*8];
            #pragma unroll
            for (int nt = 0; nt < 4; ++nt){
                s16x8 b = *(const s16x8*)&Ws[nt*16 + col][ks*32 + quad*8];
                acc[nt] = __builtin_amdgcn_mfma_f32_16x16x32_bf16(a, b, acc[nt], 0, 0, 0);
            }
        }
        __syncthreads();
    }
    #pragma unroll
    for (int nt = 0; nt < 4; ++nt){
        int n = n0 + nt*16 + col;
        float bv = bias ? bias[n] : 0.0f;
        #pragma unroll
        for (int r = 0; r < 4; ++r){
            int m = m0 + w*16 + quad*4 + r;
            float v = acc[nt][r] + bv;
            if (remap){
                int b = m & 63, t = m >> 6;
                ((float*)out)[(size_t)(b*T_ + t)*V_ + n] = v;
            } else {
                ((u16*)out)[(size_t)m*N + n] = f2bf(v);
            }
        }
    }
}

// ---------------------------------------------------------------------------
// K5: attention with online softmax. One block = (b, tile of 32 t's).
// thread: t = t_base + tid/8, d-chunk = (tid&7)*32 .. +31.
// ctx written to HC[t*B+b][256:512] (bf16).
// ---------------------------------------------------------------------------
__global__ __launch_bounds__(256) void k_attn(const u16* __restrict__ P,
                                              const u16* __restrict__ Q,
                                              const float* __restrict__ v_attn,
                                              u16* __restrict__ HC){
    __shared__ float ps[8*36];   // 32-float chunks padded to 36
    __shared__ float hs[8*36];
    int tid = threadIdx.x;
    int b   = blockIdx.x >> 4;
    int tl  = 15 - (blockIdx.x & 15);   // big tiles dispatched first
    int t_base = tl * 32;
    int t   = t_base + (tid >> 3);
    int dg  = tid & 7;
    int d0  = dg * 32;

    float q[32], vv[32], ca[32];
    #pragma unroll
    for (int i = 0; i < 32; ++i){
        q[i]  = bf2f(Q[(size_t)(t*B_ + b)*D_ + d0 + i]);
        vv[i] = v_attn[d0 + i];
        ca[i] = 0.0f;
    }
    float m_run = -1e30f, l_run = 0.0f;
    int t_lim = t_base + 31;           // iterate tp = 0 .. t_lim-1

    int sw = (tid >> 5) * 36 + (tid & 31);   // padded LDS slot for d=tid
    float rp = bf2f(P [(size_t)(0*B_ + b)*D_  + tid]);
    float rh = bf2f(HC[(size_t)(0*B_ + b)*D2_ + tid]);

    for (int tp = 0; tp < t_lim; ++tp){
        __syncthreads();               // previous iter consumers done
        ps[sw] = rp;
        hs[sw] = rh;
        __syncthreads();
        int tnx = (tp + 1 < t_lim) ? tp + 1 : tp;
        rp = bf2f(P [(size_t)(tnx*B_ + b)*D_  + tid]);
        rh = bf2f(HC[(size_t)(tnx*B_ + b)*D2_ + tid]);

        if (tp < t){
            float e = 0.0f;
            #pragma unroll
            for (int i4 = 0; i4 < 8; ++i4){
                float4 pv = *(const float4*)&ps[dg*36 + 4*i4];
                #pragma unroll
                for (int j = 0; j < 4; ++j){
                    float s = ((const float*)&pv)[j] + q[4*i4 + j];
                    e += vv[4*i4 + j] * tanh_fast(s);
                }
            }
            e += __shfl_xor(e, 1);
            e += __shfl_xor(e, 2);
            e += __shfl_xor(e, 4);
            float mn = fmaxf(m_run, e);
            float al = __expf(m_run - mn);
            float pe = __expf(e - mn);
            l_run = l_run * al + pe;
            #pragma unroll
            for (int i4 = 0; i4 < 8; ++i4){
                float4 hv = *(const float4*)&hs[dg*36 + 4*i4];
                #pragma unroll
                for (int j = 0; j < 4; ++j)
                    ca[4*i4 + j] = ca[4*i4 + j]*al + pe*((const float*)&hv)[j];
            }
            m_run = mn;
        }
    }

    if (t == 0){
        #pragma unroll
        for (int i = 0; i < 32; ++i)
            HC[(size_t)(0*B_ + b)*D2_ + 256 + d0 + i] = HC[(size_t)(0*B_ + b)*D2_ + d0 + i];
    } else {
        float rinv = 1.0f / l_run;
        #pragma unroll
        for (int i = 0; i < 32; ++i)
            HC[(size_t)(t*B_ + b)*D2_ + 256 + d0 + i] = f2bf(ca[i] * rinv);
    }
}

// ---------------------------------------------------------------------------
extern "C" void kernel_launch(void* const* d_in, const int* in_sizes, int n_in,
                              void* d_out, int out_size, void* d_ws, size_t ws_size,
                              hipStream_t stream){
    const int*   x     = (const int*)d_in[0];
    const float* embed = (const float*)d_in[1];
    const float* W_ih  = (const float*)d_in[2];
    const float* W_hh  = (const float*)d_in[3];
    const float* b_h   = (const float*)d_in[4];
    const float* W_att = (const float*)d_in[5];
    const float* U_att = (const float*)d_in[6];
    const float* v_att = (const float*)d_in[7];
    const float* fc_W  = (const float*)d_in[8];
    const float* fc_b  = (const float*)d_in[9];

    char* ws = (char*)d_ws;
    float* EW = (float*)ws;                                   // 512*256*4    = 0.5 MB
    u16*   HC = (u16*)(ws + 524288);                          // 32768*512*2  = 32 MB ([h|ctx] bf16)
    u16*   P  = (u16*)(ws + 524288 + 33554432);               // 16 MB bf16
    u16*   Q  = (u16*)(ws + 524288 + 33554432 + 16777216);    // 16 MB bf16

    k_ew  <<<dim3(V_),      dim3(256), 0, stream>>>(embed, W_ih, b_h, EW);
    k_rnn <<<dim3(4),       dim3(512), 0, stream>>>(x, EW, W_hh, HC);
    k_gemm<<<dim3(512, 4),  dim3(256), 0, stream>>>(HC, D2_, W_att, nullptr, (void*)P, D_, D_, 0);
    k_gemm<<<dim3(512, 4),  dim3(256), 0, stream>>>(HC, D2_, U_att, nullptr, (void*)Q, D_, D_, 0);
    k_attn<<<dim3(B_*16),   dim3(256), 0, stream>>>(P, Q, v_att, HC);
    k_gemm<<<dim3(512, 8),  dim3(256), 0, stream>>>(HC, D2_, fc_W, fc_b, d_out, D2_, V_, 1);
}

// Round 3
// 1732.468 us; speedup vs baseline: 1.7750x; 1.7750x over previous
//
#include <hip/hip_runtime.h>
#include <hip/hip_bf16.h>

#define B_  64
#define T_  512
#define V_  512
#define E_  128
#define D_  256
#define D2_ 512

typedef unsigned short u16;
typedef unsigned int   u32;
typedef short s16x8 __attribute__((ext_vector_type(8)));
typedef float f32x4 __attribute__((ext_vector_type(4)));
typedef unsigned short u16x2 __attribute__((ext_vector_type(2)));
typedef unsigned short u16x4 __attribute__((ext_vector_type(4)));

__device__ __forceinline__ float bf2f(u16 u){
    union { u32 i; float f; } c; c.i = ((u32)u) << 16; return c.f;
}
__device__ __forceinline__ u16 f2bf(float f){
    union { float f; u32 i; } c; c.f = f;
    u32 u = c.i;
    return (u16)((u + 0x7fffu + ((u >> 16) & 1u)) >> 16);
}
__device__ __forceinline__ float tanh_fast(float x){
    float a = fminf(fabsf(x), 15.0f);
    float e = __expf(2.0f * a);
    float r = (e - 1.0f) * __builtin_amdgcn_rcpf(e + 1.0f);
    return copysignf(r, x);
}

// ---------------------------------------------------------------------------
// K1: EW[v,d] = sum_e embed[v,e] * W_ih[e,d] + b_h[d]   (512 x 256, fp32 exact)
// ---------------------------------------------------------------------------
__global__ __launch_bounds__(256) void k_ew(const float* __restrict__ embed,
                                            const float* __restrict__ W_ih,
                                            const float* __restrict__ b_h,
                                            float* __restrict__ EW){
    __shared__ float er[E_];
    int v = blockIdx.x;
    int tid = threadIdx.x;
    if (tid < E_) er[tid] = embed[v*E_ + tid];
    __syncthreads();
    float acc = b_h[tid];
    #pragma unroll 4
    for (int e = 0; e < E_; ++e) acc += er[e] * W_ih[e*D_ + tid];
    EW[v*D_ + tid] = acc;
}

// ---------------------------------------------------------------------------
// K2: sequential h-chain. 4 blocks x 16 batches, 512 threads (8 waves).
// h and W_hh both bf16 hi+lo split (3 MFMA passes ~ fp32 recurrence).
// Double-buffered h LDS => ONE barrier per step.
// ---------------------------------------------------------------------------
__global__ __launch_bounds__(512, 2) void k_rnn(const int* __restrict__ x,
                                                const float* __restrict__ EW,
                                                const float* __restrict__ W_hh,
                                                u16* __restrict__ HC){
    __shared__ u16 hhi[2][16][264];
    __shared__ u16 hlo[2][16][264];
    int tid  = threadIdx.x;
    int lane = tid & 63;
    int w    = tid >> 6;          // wave id 0..7: n-range w*32..w*32+31
    int col  = lane & 15;
    int quad = lane >> 4;
    int bb0  = blockIdx.x * 16;

    // Preload W_hh B-fragments (hi+lo): k = ks*32+quad*8+j, n = w*32+nt*16+col
    s16x8 bfh[2][8], bfl[2][8];
    #pragma unroll
    for (int nt = 0; nt < 2; ++nt){
        int n = w*32 + nt*16 + col;
        #pragma unroll
        for (int ks = 0; ks < 8; ++ks){
            s16x8 th, tl;
            #pragma unroll
            for (int j = 0; j < 8; ++j){
                int k = ks*32 + quad*8 + j;
                float wv = W_hh[k*D_ + n];
                u16 hi = f2bf(wv);
                u16 lo = f2bf(wv - bf2f(hi));
                th[j] = (short)hi;
                tl[j] = (short)lo;
            }
            bfh[nt][ks] = th;
            bfl[nt][ks] = tl;
        }
    }
    for (int i = tid; i < 2*16*264; i += 512){
        (&hhi[0][0][0])[i] = 0; (&hlo[0][0][0])[i] = 0;
    }
    __syncthreads();

    int xr[4];
    float ewv[2][4];
    {   // prefetch xp for t=0
        #pragma unroll
        for (int r = 0; r < 4; ++r) xr[r] = x[(bb0 + quad*4 + r)*T_ + 0];
        #pragma unroll
        for (int nt = 0; nt < 2; ++nt)
            #pragma unroll
            for (int r = 0; r < 4; ++r)
                ewv[nt][r] = EW[xr[r]*D_ + w*32 + nt*16 + col];
    }

    for (int t = 0; t < T_; ++t){
        int rb = t & 1, wb = rb ^ 1;
        f32x4 accA[2], accB[2];
        #pragma unroll
        for (int nt = 0; nt < 2; ++nt)
            #pragma unroll
            for (int r = 0; r < 4; ++r){ accA[nt][r] = ewv[nt][r]; accB[nt][r] = 0.0f; }

        // prefetch next step's xp (overlaps MFMA)
        if (t + 1 < T_){
            #pragma unroll
            for (int r = 0; r < 4; ++r) xr[r] = x[(bb0 + quad*4 + r)*T_ + t + 1];
            #pragma unroll
            for (int nt = 0; nt < 2; ++nt)
                #pragma unroll
                for (int r = 0; r < 4; ++r)
                    ewv[nt][r] = EW[xr[r]*D_ + w*32 + nt*16 + col];
        }

        #pragma unroll
        for (int ks = 0; ks < 8; ++ks){
            s16x8 a_hi = *(const s16x8*)&hhi[rb][col][ks*32 + quad*8];
            s16x8 a_lo = *(const s16x8*)&hlo[rb][col][ks*32 + quad*8];
            #pragma unroll
            for (int nt = 0; nt < 2; ++nt){
                accA[nt] = __builtin_amdgcn_mfma_f32_16x16x32_bf16(a_hi, bfh[nt][ks], accA[nt], 0, 0, 0);
                accB[nt] = __builtin_amdgcn_mfma_f32_16x16x32_bf16(a_lo, bfh[nt][ks], accB[nt], 0, 0, 0);
                accB[nt] = __builtin_amdgcn_mfma_f32_16x16x32_bf16(a_hi, bfl[nt][ks], accB[nt], 0, 0, 0);
            }
        }

        #pragma unroll
        for (int nt = 0; nt < 2; ++nt){
            #pragma unroll
            for (int r = 0; r < 4; ++r){
                float h  = tanh_fast(accA[nt][r] + accB[nt][r]);
                u16 hi   = f2bf(h);
                u16 lo   = f2bf(h - bf2f(hi));
                int row  = quad*4 + r;
                int n    = w*32 + nt*16 + col;
                hhi[wb][row][n] = hi;
                hlo[wb][row][n] = lo;
                HC[(size_t)(t*B_ + bb0 + row)*D2_ + n] = hi;
            }
        }
        __syncthreads();   // h_t (wb) visible before next step reads it
    }
}

// ---------------------------------------------------------------------------
// Generic MFMA GEMM: out[M=32768, N] = A[M,K](bf16, lda) @ W[K,N](fp32->bf16)
// mode 0: out bf16 row-major.
// mode 1: out fp32, +bias, row m=t*64+b remapped to out[(b*512+t)*V + n].
// mode 2: out bf16 = exp(2*acc)  (for EP/EQ).
// ---------------------------------------------------------------------------
__global__ __launch_bounds__(256) void k_gemm(const u16* __restrict__ A, int lda,
                                              const float* __restrict__ W,
                                              const float* __restrict__ bias,
                                              void* __restrict__ out,
                                              int K, int N, int mode){
    __shared__ u16 As[64][72];
    __shared__ u16 Ws[64][72];
    int tid  = threadIdx.x;
    int lane = tid & 63;
    int w    = tid >> 6;
    int col  = lane & 15;
    int quad = lane >> 4;
    int m0   = blockIdx.x * 64;
    int n0   = blockIdx.y * 64;

    f32x4 acc[4];
    #pragma unroll
    for (int nt = 0; nt < 4; ++nt)
        #pragma unroll
        for (int r = 0; r < 4; ++r) acc[nt][r] = 0.0f;

    for (int kk = 0; kk < K; kk += 64){
        #pragma unroll
        for (int i = 0; i < 8; ++i){
            int idx = tid + i*256;
            int r   = idx >> 5;
            int c2  = (idx & 31) * 2;
            u16x2 v2 = *(const u16x2*)&A[(size_t)(m0 + r)*lda + kk + c2];
            *(u16x2*)&As[r][c2] = v2;
        }
        #pragma unroll
        for (int i = 0; i < 16; ++i){
            int idx = tid + i*256;
            int k   = idx >> 6;
            int n   = idx & 63;
            Ws[n][k] = f2bf(W[(size_t)(kk + k)*N + n0 + n]);
        }
        __syncthreads();
        #pragma unroll
        for (int ks = 0; ks < 2; ++ks){
            s16x8 a = *(const s16x8*)&As[w*16 + col][ks*32 + quad*8];
            #pragma unroll
            for (int nt = 0; nt < 4; ++nt){
                s16x8 b = *(const s16x8*)&Ws[nt*16 + col][ks*32 + quad*8];
                acc[nt] = __builtin_amdgcn_mfma_f32_16x16x32_bf16(a, b, acc[nt], 0, 0, 0);
            }
        }
        __syncthreads();
    }
    #pragma unroll
    for (int nt = 0; nt < 4; ++nt){
        int n = n0 + nt*16 + col;
        float bv = (mode == 1 && bias) ? bias[n] : 0.0f;
        #pragma unroll
        for (int r = 0; r < 4; ++r){
            int m = m0 + w*16 + quad*4 + r;
            float v = acc[nt][r] + bv;
            if (mode == 1){
                int b = m & 63, t = m >> 6;
                ((float*)out)[(size_t)(b*T_ + t)*V_ + n] = v;
            } else if (mode == 2){
                ((u16*)out)[(size_t)m*N + n] = f2bf(__expf(2.0f * v));
            } else {
                ((u16*)out)[(size_t)m*N + n] = f2bf(v);
            }
        }
    }
}

// ---------------------------------------------------------------------------
// K5: energies. Block = (b, tt, pt), pt <= tt, 32x32 (t,t') tile over d=256.
// tanh(p+q) = 1 - 2/(1 + e^{2p} e^{2q}); e = sum_d v_d * tanh(..).
// Writes Wx[b][t][t'] = bf16(exp(e)) for t'<t, atomicAdds row sums into l.
// ---------------------------------------------------------------------------
__global__ __launch_bounds__(256) void k_energy(const u16* __restrict__ EP,
                                                const u16* __restrict__ EQ,
                                                const float* __restrict__ v_attn,
                                                u16* __restrict__ Wx,
                                                float* __restrict__ l){
    __shared__ float eps[32][260];
    int tid = threadIdx.x;
    int blk = blockIdx.x;
    int b   = blk / 136;
    int pi  = blk % 136;
    int tt  = 0;
    while ((tt+1)*(tt+2)/2 <= pi) ++tt;
    int pt  = pi - tt*(tt+1)/2;

    int t_l = tid >> 3;
    int dg  = tid & 7;
    int d0  = dg * 32;
    int t   = tt*32 + t_l;

    // stage EP rows [pt*32, pt*32+32) as fp32
    #pragma unroll
    for (int i = 0; i < 8; ++i){
        int idx = tid + i*256;            // 0..2047, 4 bf16 each
        int row = idx >> 6;
        int c4  = (idx & 63) * 4;
        u16x4 v4 = *(const u16x4*)&EP[((size_t)((pt*32 + row)*B_ + b))*D_ + c4];
        float4 f4 = make_float4(bf2f(v4.x), bf2f(v4.y), bf2f(v4.z), bf2f(v4.w));
        *(float4*)&eps[row][c4] = f4;
    }

    float eq[32], vm2[32], sv = 0.0f;
    #pragma unroll
    for (int i = 0; i < 8; ++i){
        u16x4 v4 = *(const u16x4*)&EQ[((size_t)(t*B_ + b))*D_ + d0 + i*4];
        eq[i*4+0] = bf2f(v4.x); eq[i*4+1] = bf2f(v4.y);
        eq[i*4+2] = bf2f(v4.z); eq[i*4+3] = bf2f(v4.w);
    }
    #pragma unroll
    for (int i = 0; i < 32; ++i){
        float v = v_attn[d0 + i];
        sv += v;
        vm2[i] = -2.0f * v;
    }
    __syncthreads();

    float lsum = 0.0f;
    for (int tpl = 0; tpl < 32; ++tpl){
        int tp = pt*32 + tpl;
        float acc = sv;
        #pragma unroll
        for (int i4 = 0; i4 < 8; ++i4){
            float4 ep = *(const float4*)&eps[tpl][d0 + i4*4];
            acc = fmaf(vm2[i4*4+0], __builtin_amdgcn_rcpf(fmaf(ep.x, eq[i4*4+0], 1.0f)), acc);
            acc = fmaf(vm2[i4*4+1], __builtin_amdgcn_rcpf(fmaf(ep.y, eq[i4*4+1], 1.0f)), acc);
            acc = fmaf(vm2[i4*4+2], __builtin_amdgcn_rcpf(fmaf(ep.z, eq[i4*4+2], 1.0f)), acc);
            acc = fmaf(vm2[i4*4+3], __builtin_amdgcn_rcpf(fmaf(ep.w, eq[i4*4+3], 1.0f)), acc);
        }
        acc += __shfl_xor(acc, 1);
        acc += __shfl_xor(acc, 2);
        acc += __shfl_xor(acc, 4);
        float pe = __expf(acc);
        if (dg == 0 && tp < t){
            u16 peb = f2bf(pe);
            Wx[((size_t)(b*T_ + t))*T_ + tp] = peb;
            lsum += bf2f(peb);
        }
    }
    if (dg == 0 && lsum != 0.0f) atomicAdd(&l[b*T_ + t], lsum);
}

// ---------------------------------------------------------------------------
// K6: ctx[b][t][d] = (sum_t' Wx[b][t][t'] * h[t'][d]) / l[b][t]; t=0 -> h[0].
// Writes into HC[t*64+b][256+d].
// ---------------------------------------------------------------------------
__global__ __launch_bounds__(256) void k_ctx(const u16* __restrict__ Wx,
                                             u16* __restrict__ HC,
                                             const float* __restrict__ l){
    __shared__ u16 As[64][72];
    __shared__ u16 Ws[64][72];
    int tid  = threadIdx.x;
    int lane = tid & 63;
    int w    = tid >> 6;
    int col  = lane & 15;
    int quad = lane >> 4;
    int b    = blockIdx.y;
    int m0   = (blockIdx.x >> 2) * 64;   // t tile
    int n0   = (blockIdx.x & 3) * 64;    // d tile

    const u16* A = Wx + (size_t)b * T_ * T_;

    f32x4 acc[4];
    #pragma unroll
    for (int nt = 0; nt < 4; ++nt)
        #pragma unroll
        for (int r = 0; r < 4; ++r) acc[nt][r] = 0.0f;

    for (int kk = 0; kk < T_; kk += 64){
        #pragma unroll
        for (int i = 0; i < 8; ++i){
            int idx = tid + i*256;
            int r   = idx >> 5;
            int c2  = (idx & 31) * 2;
            u16x2 v2 = *(const u16x2*)&A[(size_t)(m0 + r)*T_ + kk + c2];
            *(u16x2*)&As[r][c2] = v2;
        }
        #pragma unroll
        for (int i = 0; i < 8; ++i){
            int idx = tid + i*256;
            int k   = idx >> 5;
            int n2  = (idx & 31) * 2;
            u16x2 v2 = *(const u16x2*)&HC[((size_t)((kk + k)*B_ + b))*D2_ + n0 + n2];
            Ws[n2][k]   = v2.x;
            Ws[n2+1][k] = v2.y;
        }
        __syncthreads();
        #pragma unroll
        for (int ks = 0; ks < 2; ++ks){
            s16x8 a = *(const s16x8*)&As[w*16 + col][ks*32 + quad*8];
            #pragma unroll
            for (int nt = 0; nt < 4; ++nt){
                s16x8 bb = *(const s16x8*)&Ws[nt*16 + col][ks*32 + quad*8];
                acc[nt] = __builtin_amdgcn_mfma_f32_16x16x32_bf16(a, bb, acc[nt], 0, 0, 0);
            }
        }
        __syncthreads();
    }

    float linv[4];
    #pragma unroll
    for (int r = 0; r < 4; ++r){
        int t = m0 + w*16 + quad*4 + r;
        float lv = (t > 0) ? l[b*T_ + t] : 1.0f;
        linv[r] = 1.0f / lv;
    }
    #pragma unroll
    for (int nt = 0; nt < 4; ++nt){
        int n = n0 + nt*16 + col;
        #pragma unroll
        for (int r = 0; r < 4; ++r){
            int t = m0 + w*16 + quad*4 + r;
            u16 ov;
            if (t == 0) ov = HC[(size_t)b*D2_ + n];          // ctx(0) = h(0)
            else        ov = f2bf(acc[nt][r] * linv[r]);
            HC[((size_t)(t*B_ + b))*D2_ + D_ + n] = ov;
        }
    }
}

// ---------------------------------------------------------------------------
extern "C" void kernel_launch(void* const* d_in, const int* in_sizes, int n_in,
                              void* d_out, int out_size, void* d_ws, size_t ws_size,
                              hipStream_t stream){
    const int*   x     = (const int*)d_in[0];
    const float* embed = (const float*)d_in[1];
    const float* W_ih  = (const float*)d_in[2];
    const float* W_hh  = (const float*)d_in[3];
    const float* b_h   = (const float*)d_in[4];
    const float* W_att = (const float*)d_in[5];
    const float* U_att = (const float*)d_in[6];
    const float* v_att = (const float*)d_in[7];
    const float* fc_W  = (const float*)d_in[8];
    const float* fc_b  = (const float*)d_in[9];

    char* ws = (char*)d_ws;
    float* EW = (float*)ws;                         // 0.5 MB
    u16*   HC = (u16*)(ws + 524288);                // 32 MB  [h|ctx] bf16
    u16*   EP = (u16*)(ws + 34078720);              // 16 MB  exp(2*P) bf16
    u16*   EQ = (u16*)(ws + 50855936);              // 16 MB  exp(2*Q) bf16
    float* l  = (float*)(ws + 67633152);            // 128 KB row sums
    u16*   Wx = (u16*)d_out;                        // 33.5 MB scratch in d_out (dead until fc)

    hipMemsetAsync(d_out, 0, (size_t)B_*T_*T_*2, stream);   // zero Wx (upper triangle stays 0)
    hipMemsetAsync(l, 0, B_*T_*4, stream);

    k_ew    <<<dim3(V_),       dim3(256), 0, stream>>>(embed, W_ih, b_h, EW);
    k_rnn   <<<dim3(4),        dim3(512), 0, stream>>>(x, EW, W_hh, HC);
    k_gemm  <<<dim3(512, 4),   dim3(256), 0, stream>>>(HC, D2_, W_att, nullptr, (void*)EP, D_, D_, 2);
    k_gemm  <<<dim3(512, 4),   dim3(256), 0, stream>>>(HC, D2_, U_att, nullptr, (void*)EQ, D_, D_, 2);
    k_energy<<<dim3(B_*136),   dim3(256), 0, stream>>>(EP, EQ, v_att, Wx, l);
    k_ctx   <<<dim3(32, B_),   dim3(256), 0, stream>>>(Wx, HC, l);
    k_gemm  <<<dim3(512, 8),   dim3(256), 0, stream>>>(HC, D2_, fc_W, fc_b, d_out, D2_, V_, 1);
}

// Round 4
// 1593.849 us; speedup vs baseline: 1.9294x; 1.0870x over previous
//
#include <hip/hip_runtime.h>
#include <hip/hip_bf16.h>

#define B_  64
#define T_  512
#define V_  512
#define E_  128
#define D_  256
#define D2_ 512

typedef unsigned short u16;
typedef unsigned int   u32;
typedef short s16x8 __attribute__((ext_vector_type(8)));
typedef float f32x4 __attribute__((ext_vector_type(4)));
typedef unsigned short u16x2 __attribute__((ext_vector_type(2)));
typedef unsigned short u16x4 __attribute__((ext_vector_type(4)));

__device__ __forceinline__ float bf2f(u16 u){
    union { u32 i; float f; } c; c.i = ((u32)u) << 16; return c.f;
}
__device__ __forceinline__ u16 f2bf(float f){
    union { float f; u32 i; } c; c.f = f;
    u32 u = c.i;
    return (u16)((u + 0x7fffu + ((u >> 16) & 1u)) >> 16);
}
__device__ __forceinline__ float tanh_fast(float x){
    float a = fminf(fabsf(x), 15.0f);
    float e = __expf(2.0f * a);
    float r = (e - 1.0f) * __builtin_amdgcn_rcpf(e + 1.0f);
    return copysignf(r, x);
}

// ---------------------------------------------------------------------------
// K1: EW[v,d] = sum_e embed[v,e] * W_ih[e,d] + b_h[d]   (512 x 256, fp32 exact)
// ---------------------------------------------------------------------------
__global__ __launch_bounds__(256) void k_ew(const float* __restrict__ embed,
                                            const float* __restrict__ W_ih,
                                            const float* __restrict__ b_h,
                                            float* __restrict__ EW){
    __shared__ float er[E_];
    int v = blockIdx.x;
    int tid = threadIdx.x;
    if (tid < E_) er[tid] = embed[v*E_ + tid];
    __syncthreads();
    float acc = b_h[tid];
    #pragma unroll 4
    for (int e = 0; e < E_; ++e) acc += er[e] * W_ih[e*D_ + tid];
    EW[v*D_ + tid] = acc;
}

// ---------------------------------------------------------------------------
// K2: sequential h-chain. 8 blocks x 8 batches (M=8), 512 threads (8 waves).
// h and W_hh both bf16 hi+lo split (3 MFMA passes ~ fp32 recurrence).
// LDS row stride 272 u16 (136 dwords == 8 mod 32): conflict-free b128 reads.
// A-frag lanes col>=8 alias col&7 (broadcast, free) -> half LDS BW.
// ---------------------------------------------------------------------------
__global__ __launch_bounds__(512, 2) void k_rnn(const int* __restrict__ x,
                                                const float* __restrict__ EW,
                                                const float* __restrict__ W_hh,
                                                u16* __restrict__ HC){
    __shared__ u16 hhi[2][8][272];
    __shared__ u16 hlo[2][8][272];
    int tid  = threadIdx.x;
    int lane = tid & 63;
    int w    = tid >> 6;          // wave id 0..7: n-range w*32..w*32+31
    int col  = lane & 15;
    int colA = col & 7;           // aliased A-row (rows 8..15 duplicate 0..7)
    int quad = lane >> 4;
    int bb0  = blockIdx.x * 8;
    bool act = (quad < 2);        // C rows 0..7 live in quads 0,1

    // Preload W_hh B-fragments (hi+lo): k = ks*32+quad*8+j, n = w*32+nt*16+col
    s16x8 bfh[2][8], bfl[2][8];
    #pragma unroll
    for (int nt = 0; nt < 2; ++nt){
        int n = w*32 + nt*16 + col;
        #pragma unroll
        for (int ks = 0; ks < 8; ++ks){
            s16x8 th, tl;
            #pragma unroll
            for (int j = 0; j < 8; ++j){
                int k = ks*32 + quad*8 + j;
                float wv = W_hh[k*D_ + n];
                u16 hi = f2bf(wv);
                u16 lo = f2bf(wv - bf2f(hi));
                th[j] = (short)hi;
                tl[j] = (short)lo;
            }
            bfh[nt][ks] = th;
            bfl[nt][ks] = tl;
        }
    }
    for (int i = tid; i < 2*8*272; i += 512){
        (&hhi[0][0][0])[i] = 0; (&hlo[0][0][0])[i] = 0;
    }
    __syncthreads();

    int xr[4];
    float ewv[2][4] = {{0,0,0,0},{0,0,0,0}};
    if (act){   // prefetch xp for t=0 (rows quad*4+r = 0..7)
        #pragma unroll
        for (int r = 0; r < 4; ++r) xr[r] = x[(bb0 + quad*4 + r)*T_ + 0];
        #pragma unroll
        for (int nt = 0; nt < 2; ++nt)
            #pragma unroll
            for (int r = 0; r < 4; ++r)
                ewv[nt][r] = EW[xr[r]*D_ + w*32 + nt*16 + col];
    }

    for (int t = 0; t < T_; ++t){
        int rb = t & 1, wb = rb ^ 1;
        f32x4 accA[2], accB[2];
        #pragma unroll
        for (int nt = 0; nt < 2; ++nt)
            #pragma unroll
            for (int r = 0; r < 4; ++r){ accA[nt][r] = ewv[nt][r]; accB[nt][r] = 0.0f; }

        // prefetch next step's xp (overlaps MFMA)
        if (act && t + 1 < T_){
            #pragma unroll
            for (int r = 0; r < 4; ++r) xr[r] = x[(bb0 + quad*4 + r)*T_ + t + 1];
            #pragma unroll
            for (int nt = 0; nt < 2; ++nt)
                #pragma unroll
                for (int r = 0; r < 4; ++r)
                    ewv[nt][r] = EW[xr[r]*D_ + w*32 + nt*16 + col];
        }

        #pragma unroll
        for (int ks = 0; ks < 8; ++ks){
            s16x8 a_hi = *(const s16x8*)&hhi[rb][colA][ks*32 + quad*8];
            s16x8 a_lo = *(const s16x8*)&hlo[rb][colA][ks*32 + quad*8];
            #pragma unroll
            for (int nt = 0; nt < 2; ++nt){
                accA[nt] = __builtin_amdgcn_mfma_f32_16x16x32_bf16(a_hi, bfh[nt][ks], accA[nt], 0, 0, 0);
                accB[nt] = __builtin_amdgcn_mfma_f32_16x16x32_bf16(a_lo, bfh[nt][ks], accB[nt], 0, 0, 0);
                accB[nt] = __builtin_amdgcn_mfma_f32_16x16x32_bf16(a_hi, bfl[nt][ks], accB[nt], 0, 0, 0);
            }
        }

        if (act){
            #pragma unroll
            for (int nt = 0; nt < 2; ++nt){
                #pragma unroll
                for (int r = 0; r < 4; ++r){
                    float h  = tanh_fast(accA[nt][r] + accB[nt][r]);
                    u16 hi   = f2bf(h);
                    u16 lo   = f2bf(h - bf2f(hi));
                    int row  = quad*4 + r;        // 0..7
                    int n    = w*32 + nt*16 + col;
                    hhi[wb][row][n] = hi;
                    hlo[wb][row][n] = lo;
                    HC[(size_t)(t*B_ + bb0 + row)*D2_ + n] = hi;
                }
            }
        }
        __syncthreads();   // h_t (wb) visible before next step reads it
    }
}

// ---------------------------------------------------------------------------
// Generic MFMA GEMM: out[M=32768, N] = A[M,K](bf16, lda) @ W[K,N](fp32->bf16)
// mode 0: out bf16 row-major.
// mode 1: out fp32, +bias, row m=t*64+b remapped to out[(b*512+t)*V + n].
// mode 2: out bf16 = exp(2*acc)  (for EP/EQ).
// ---------------------------------------------------------------------------
__global__ __launch_bounds__(256) void k_gemm(const u16* __restrict__ A, int lda,
                                              const float* __restrict__ W,
                                              const float* __restrict__ bias,
                                              void* __restrict__ out,
                                              int K, int N, int mode){
    __shared__ u16 As[64][72];
    __shared__ u16 Ws[64][72];
    int tid  = threadIdx.x;
    int lane = tid & 63;
    int w    = tid >> 6;
    int col  = lane & 15;
    int quad = lane >> 4;
    int m0   = blockIdx.x * 64;
    int n0   = blockIdx.y * 64;

    f32x4 acc[4];
    #pragma unroll
    for (int nt = 0; nt < 4; ++nt)
        #pragma unroll
        for (int r = 0; r < 4; ++r) acc[nt][r] = 0.0f;

    for (int kk = 0; kk < K; kk += 64){
        #pragma unroll
        for (int i = 0; i < 8; ++i){
            int idx = tid + i*256;
            int r   = idx >> 5;
            int c2  = (idx & 31) * 2;
            u16x2 v2 = *(const u16x2*)&A[(size_t)(m0 + r)*lda + kk + c2];
            *(u16x2*)&As[r][c2] = v2;
        }
        #pragma unroll
        for (int i = 0; i < 16; ++i){
            int idx = tid + i*256;
            int k   = idx >> 6;
            int n   = idx & 63;
            Ws[n][k] = f2bf(W[(size_t)(kk + k)*N + n0 + n]);
        }
        __syncthreads();
        #pragma unroll
        for (int ks = 0; ks < 2; ++ks){
            s16x8 a = *(const s16x8*)&As[w*16 + col][ks*32 + quad*8];
            #pragma unroll
            for (int nt = 0; nt < 4; ++nt){
                s16x8 b = *(const s16x8*)&Ws[nt*16 + col][ks*32 + quad*8];
                acc[nt] = __builtin_amdgcn_mfma_f32_16x16x32_bf16(a, b, acc[nt], 0, 0, 0);
            }
        }
        __syncthreads();
    }
    #pragma unroll
    for (int nt = 0; nt < 4; ++nt){
        int n = n0 + nt*16 + col;
        float bv = (mode == 1 && bias) ? bias[n] : 0.0f;
        #pragma unroll
        for (int r = 0; r < 4; ++r){
            int m = m0 + w*16 + quad*4 + r;
            float v = acc[nt][r] + bv;
            if (mode == 1){
                int b = m & 63, t = m >> 6;
                ((float*)out)[(size_t)(b*T_ + t)*V_ + n] = v;
            } else if (mode == 2){
                ((u16*)out)[(size_t)m*N + n] = f2bf(__expf(2.0f * v));
            } else {
                ((u16*)out)[(size_t)m*N + n] = f2bf(v);
            }
        }
    }
}

// ---------------------------------------------------------------------------
// K5: energies. Block = (b, tt, pt), pt <= tt, 32x32 (t,t') tile over d=256.
// tanh(p+q) = 1 - 2/(1 + e^{2p} e^{2q}); e = sum_d v_d * tanh(..).
// eps layout: 8 chunks of 32 floats padded to 36 dwords -> conflict-free
// float4 reads at dg*36 (8 windows x 4 banks tile all 32 banks).
// ---------------------------------------------------------------------------
__global__ __launch_bounds__(256) void k_energy(const u16* __restrict__ EP,
                                                const u16* __restrict__ EQ,
                                                const float* __restrict__ v_attn,
                                                u16* __restrict__ Wx,
                                                float* __restrict__ l){
    __shared__ float eps[32][288];
    int tid = threadIdx.x;
    int blk = blockIdx.x;
    int b   = blk / 136;
    int pi  = blk % 136;
    int tt  = 0;
    while ((tt+1)*(tt+2)/2 <= pi) ++tt;
    int pt  = pi - tt*(tt+1)/2;

    int t_l = tid >> 3;
    int dg  = tid & 7;
    int d0  = dg * 32;
    int t   = tt*32 + t_l;

    // stage EP rows [pt*32, pt*32+32) as fp32 into padded layout
    #pragma unroll
    for (int i = 0; i < 8; ++i){
        int idx = tid + i*256;            // 0..2047, 4 bf16 each
        int row = idx >> 6;
        int c4  = (idx & 63) * 4;
        int pc  = c4 + ((c4 >> 5) << 2);  // +4 dwords per 32-chunk
        u16x4 v4 = *(const u16x4*)&EP[((size_t)((pt*32 + row)*B_ + b))*D_ + c4];
        float4 f4 = make_float4(bf2f(v4.x), bf2f(v4.y), bf2f(v4.z), bf2f(v4.w));
        *(float4*)&eps[row][pc] = f4;
    }

    float eq[32], vm2[32], sv = 0.0f;
    #pragma unroll
    for (int i = 0; i < 8; ++i){
        u16x4 v4 = *(const u16x4*)&EQ[((size_t)(t*B_ + b))*D_ + d0 + i*4];
        eq[i*4+0] = bf2f(v4.x); eq[i*4+1] = bf2f(v4.y);
        eq[i*4+2] = bf2f(v4.z); eq[i*4+3] = bf2f(v4.w);
    }
    #pragma unroll
    for (int i = 0; i < 32; ++i){
        float v = v_attn[d0 + i];
        sv += v;
        vm2[i] = -2.0f * v;
    }
    __syncthreads();

    float lsum = 0.0f;
    for (int tpl = 0; tpl < 32; ++tpl){
        int tp = pt*32 + tpl;
        float acc = sv;
        #pragma unroll
        for (int i4 = 0; i4 < 8; ++i4){
            float4 ep = *(const float4*)&eps[tpl][dg*36 + 4*i4];
            acc = fmaf(vm2[i4*4+0], __builtin_amdgcn_rcpf(fmaf(ep.x, eq[i4*4+0], 1.0f)), acc);
            acc = fmaf(vm2[i4*4+1], __builtin_amdgcn_rcpf(fmaf(ep.y, eq[i4*4+1], 1.0f)), acc);
            acc = fmaf(vm2[i4*4+2], __builtin_amdgcn_rcpf(fmaf(ep.z, eq[i4*4+2], 1.0f)), acc);
            acc = fmaf(vm2[i4*4+3], __builtin_amdgcn_rcpf(fmaf(ep.w, eq[i4*4+3], 1.0f)), acc);
        }
        acc += __shfl_xor(acc, 1);
        acc += __shfl_xor(acc, 2);
        acc += __shfl_xor(acc, 4);
        float pe = __expf(acc);
        if (dg == 0 && tp < t){
            u16 peb = f2bf(pe);
            Wx[((size_t)(b*T_ + t))*T_ + tp] = peb;
            lsum += bf2f(peb);
        }
    }
    if (dg == 0 && lsum != 0.0f) atomicAdd(&l[b*T_ + t], lsum);
}

// ---------------------------------------------------------------------------
// K6: ctx[b][t][d] = (sum_t' Wx[b][t][t'] * h[t'][d]) / l[b][t]; t=0 -> h[0].
// Writes into HC[t*64+b][256+d].
// ---------------------------------------------------------------------------
__global__ __launch_bounds__(256) void k_ctx(const u16* __restrict__ Wx,
                                             u16* __restrict__ HC,
                                             const float* __restrict__ l){
    __shared__ u16 As[64][72];
    __shared__ u16 Ws[64][72];
    int tid  = threadIdx.x;
    int lane = tid & 63;
    int w    = tid >> 6;
    int col  = lane & 15;
    int quad = lane >> 4;
    int b    = blockIdx.y;
    int m0   = (blockIdx.x >> 2) * 64;   // t tile
    int n0   = (blockIdx.x & 3) * 64;    // d tile

    const u16* A = Wx + (size_t)b * T_ * T_;

    f32x4 acc[4];
    #pragma unroll
    for (int nt = 0; nt < 4; ++nt)
        #pragma unroll
        for (int r = 0; r < 4; ++r) acc[nt][r] = 0.0f;

    for (int kk = 0; kk < T_; kk += 64){
        #pragma unroll
        for (int i = 0; i < 8; ++i){
            int idx = tid + i*256;
            int r   = idx >> 5;
            int c2  = (idx & 31) * 2;
            u16x2 v2 = *(const u16x2*)&A[(size_t)(m0 + r)*T_ + kk + c2];
            *(u16x2*)&As[r][c2] = v2;
        }
        #pragma unroll
        for (int i = 0; i < 8; ++i){
            int idx = tid + i*256;
            int k   = idx >> 5;
            int n2  = (idx & 31) * 2;
            u16x2 v2 = *(const u16x2*)&HC[((size_t)((kk + k)*B_ + b))*D2_ + n0 + n2];
            Ws[n2][k]   = v2.x;
            Ws[n2+1][k] = v2.y;
        }
        __syncthreads();
        #pragma unroll
        for (int ks = 0; ks < 2; ++ks){
            s16x8 a = *(const s16x8*)&As[w*16 + col][ks*32 + quad*8];
            #pragma unroll
            for (int nt = 0; nt < 4; ++nt){
                s16x8 bb = *(const s16x8*)&Ws[nt*16 + col][ks*32 + quad*8];
                acc[nt] = __builtin_amdgcn_mfma_f32_16x16x32_bf16(a, bb, acc[nt], 0, 0, 0);
            }
        }
        __syncthreads();
    }

    float linv[4];
    #pragma unroll
    for (int r = 0; r < 4; ++r){
        int t = m0 + w*16 + quad*4 + r;
        float lv = (t > 0) ? l[b*T_ + t] : 1.0f;
        linv[r] = 1.0f / lv;
    }
    #pragma unroll
    for (int nt = 0; nt < 4; ++nt){
        int n = n0 + nt*16 + col;
        #pragma unroll
        for (int r = 0; r < 4; ++r){
            int t = m0 + w*16 + quad*4 + r;
            u16 ov;
            if (t == 0) ov = HC[(size_t)b*D2_ + n];          // ctx(0) = h(0)
            else        ov = f2bf(acc[nt][r] * linv[r]);
            HC[((size_t)(t*B_ + b))*D2_ + D_ + n] = ov;
        }
    }
}

// ---------------------------------------------------------------------------
extern "C" void kernel_launch(void* const* d_in, const int* in_sizes, int n_in,
                              void* d_out, int out_size, void* d_ws, size_t ws_size,
                              hipStream_t stream){
    const int*   x     = (const int*)d_in[0];
    const float* embed = (const float*)d_in[1];
    const float* W_ih  = (const float*)d_in[2];
    const float* W_hh  = (const float*)d_in[3];
    const float* b_h   = (const float*)d_in[4];
    const float* W_att = (const float*)d_in[5];
    const float* U_att = (const float*)d_in[6];
    const float* v_att = (const float*)d_in[7];
    const float* fc_W  = (const float*)d_in[8];
    const float* fc_b  = (const float*)d_in[9];

    char* ws = (char*)d_ws;
    float* EW = (float*)ws;                         // 0.5 MB
    u16*   HC = (u16*)(ws + 524288);                // 32 MB  [h|ctx] bf16
    u16*   EP = (u16*)(ws + 34078720);              // 16 MB  exp(2*P) bf16
    u16*   EQ = (u16*)(ws + 50855936);              // 16 MB  exp(2*Q) bf16
    float* l  = (float*)(ws + 67633152);            // 128 KB row sums
    u16*   Wx = (u16*)d_out;                        // 33.5 MB scratch in d_out (dead until fc)

    hipMemsetAsync(d_out, 0, (size_t)B_*T_*T_*2, stream);   // zero Wx (upper triangle stays 0)
    hipMemsetAsync(l, 0, B_*T_*4, stream);

    k_ew    <<<dim3(V_),       dim3(256), 0, stream>>>(embed, W_ih, b_h, EW);
    k_rnn   <<<dim3(8),        dim3(512), 0, stream>>>(x, EW, W_hh, HC);
    k_gemm  <<<dim3(512, 4),   dim3(256), 0, stream>>>(HC, D2_, W_att, nullptr, (void*)EP, D_, D_, 2);
    k_gemm  <<<dim3(512, 4),   dim3(256), 0, stream>>>(HC, D2_, U_att, nullptr, (void*)EQ, D_, D_, 2);
    k_energy<<<dim3(B_*136),   dim3(256), 0, stream>>>(EP, EQ, v_att, Wx, l);
    k_ctx   <<<dim3(32, B_),   dim3(256), 0, stream>>>(Wx, HC, l);
    k_gemm  <<<dim3(512, 8),   dim3(256), 0, stream>>>(HC, D2_, fc_W, fc_b, d_out, D2_, V_, 1);
}

// Round 5
// 1291.469 us; speedup vs baseline: 2.3812x; 1.2341x over previous
//
#include <hip/hip_runtime.h>
#include <hip/hip_bf16.h>

#define B_  64
#define T_  512
#define V_  512
#define E_  128
#define D_  256
#define D2_ 512

typedef unsigned short u16;
typedef unsigned int   u32;
typedef short s16x8 __attribute__((ext_vector_type(8)));
typedef float f32x4 __attribute__((ext_vector_type(4)));
typedef unsigned short u16x2 __attribute__((ext_vector_type(2)));
typedef unsigned short u16x4 __attribute__((ext_vector_type(4)));

__device__ __forceinline__ float bf2f(u16 u){
    union { u32 i; float f; } c; c.i = ((u32)u) << 16; return c.f;
}
__device__ __forceinline__ u16 f2bf(float f){
    union { float f; u32 i; } c; c.f = f;
    u32 u = c.i;
    return (u16)((u + 0x7fffu + ((u >> 16) & 1u)) >> 16);
}
__device__ __forceinline__ float tanh_fast(float x){
    float a = fminf(fabsf(x), 15.0f);
    float e = __expf(2.0f * a);
    float r = (e - 1.0f) * __builtin_amdgcn_rcpf(e + 1.0f);
    return copysignf(r, x);
}
// tanh for bounded args (|x| <~ 20): 1 - 2/(e^{2x}+1). No clamp/abs needed.
__device__ __forceinline__ float tanh_b(float x){
    float e = __expf(2.0f * x);
    return fmaf(-2.0f, __builtin_amdgcn_rcpf(e + 1.0f), 1.0f);
}

// ---------------------------------------------------------------------------
// K1: EW[v,d] = sum_e embed[v,e] * W_ih[e,d] + b_h[d]   (512 x 256, fp32 exact)
// ---------------------------------------------------------------------------
__global__ __launch_bounds__(256) void k_ew(const float* __restrict__ embed,
                                            const float* __restrict__ W_ih,
                                            const float* __restrict__ b_h,
                                            float* __restrict__ EW){
    __shared__ float er[E_];
    int v = blockIdx.x;
    int tid = threadIdx.x;
    if (tid < E_) er[tid] = embed[v*E_ + tid];
    __syncthreads();
    float acc = b_h[tid];
    #pragma unroll 4
    for (int e = 0; e < E_; ++e) acc += er[e] * W_ih[e*D_ + tid];
    EW[v*D_ + tid] = acc;
}

// ---------------------------------------------------------------------------
// K2: sequential h-chain. 16 blocks x 4 batches (M=4), 512 threads (8 waves).
// h kept as bf16 hi+lo (2 MFMA passes vs single-bf16 W: ~2e-3 systematic err).
// Epilogue repacked via per-wave LDS scratch so all 64 lanes do tanh work.
// LDS row stride 272 u16 (136 dw == 8 mod 32): A-frag b128 reads <=2-way.
// ---------------------------------------------------------------------------
__global__ __launch_bounds__(512, 2) void k_rnn(const int* __restrict__ x,
                                                const float* __restrict__ EW,
                                                const float* __restrict__ W_hh,
                                                u16* __restrict__ HC){
    __shared__ u16 hhi[2][4][272];
    __shared__ u16 hlo[2][4][272];
    __shared__ float scr[8][16][10];   // [wave][col][v(8)+pad2]
    int tid  = threadIdx.x;
    int lane = tid & 63;
    int w    = tid >> 6;          // wave 0..7: n-range w*32..w*32+31
    int col  = lane & 15;
    int colA = col & 3;           // A-row alias (rows 4..15 duplicate 0..3)
    int quad = lane >> 4;
    int bb0  = blockIdx.x * 4;

    // Preload W_hh B-fragments (single bf16): k = ks*32+quad*8+j, n = w*32+nt*16+col
    s16x8 bfh[2][8];
    #pragma unroll
    for (int nt = 0; nt < 2; ++nt){
        int n = w*32 + nt*16 + col;
        #pragma unroll
        for (int ks = 0; ks < 8; ++ks){
            s16x8 th;
            #pragma unroll
            for (int j = 0; j < 8; ++j){
                int k = ks*32 + quad*8 + j;
                th[j] = (short)f2bf(W_hh[k*D_ + n]);
            }
            bfh[nt][ks] = th;
        }
    }
    for (int i = tid; i < 2*4*272; i += 512){
        (&hhi[0][0][0])[i] = 0; (&hlo[0][0][0])[i] = 0;
    }
    __syncthreads();

    int xr[4];
    float ewv[2][4] = {{0,0,0,0},{0,0,0,0}};
    if (quad == 0){   // C rows 0..3 live on quad 0
        #pragma unroll
        for (int r = 0; r < 4; ++r) xr[r] = x[(bb0 + r)*T_ + 0];
        #pragma unroll
        for (int nt = 0; nt < 2; ++nt)
            #pragma unroll
            for (int r = 0; r < 4; ++r)
                ewv[nt][r] = EW[xr[r]*D_ + w*32 + nt*16 + col];
    }

    for (int t = 0; t < T_; ++t){
        int rb = t & 1, wb = rb ^ 1;
        f32x4 accH[2], accL[2];
        #pragma unroll
        for (int nt = 0; nt < 2; ++nt)
            #pragma unroll
            for (int r = 0; r < 4; ++r){ accH[nt][r] = ewv[nt][r]; accL[nt][r] = 0.0f; }

        // prefetch next step's xp (overlaps MFMA)
        if (quad == 0 && t + 1 < T_){
            #pragma unroll
            for (int r = 0; r < 4; ++r) xr[r] = x[(bb0 + r)*T_ + t + 1];
            #pragma unroll
            for (int nt = 0; nt < 2; ++nt)
                #pragma unroll
                for (int r = 0; r < 4; ++r)
                    ewv[nt][r] = EW[xr[r]*D_ + w*32 + nt*16 + col];
        }

        #pragma unroll
        for (int ks = 0; ks < 8; ++ks){
            s16x8 a_hi = *(const s16x8*)&hhi[rb][colA][ks*32 + quad*8];
            s16x8 a_lo = *(const s16x8*)&hlo[rb][colA][ks*32 + quad*8];
            #pragma unroll
            for (int nt = 0; nt < 2; ++nt){
                accH[nt] = __builtin_amdgcn_mfma_f32_16x16x32_bf16(a_hi, bfh[nt][ks], accH[nt], 0, 0, 0);
                accL[nt] = __builtin_amdgcn_mfma_f32_16x16x32_bf16(a_lo, bfh[nt][ks], accL[nt], 0, 0, 0);
            }
        }

        // repack: quad0's 8 C-values -> per-wave scratch -> 2 per lane full-wave
        if (quad == 0){
            f32x4 v0, v1;
            #pragma unroll
            for (int r = 0; r < 4; ++r){ v0[r] = accH[0][r] + accL[0][r]; v1[r] = accH[1][r] + accL[1][r]; }
            *(f32x4*)&scr[w][col][0] = v0;   // v = nt*4+r : 0..3
            *(f32x4*)&scr[w][col][4] = v1;   // 4..7
        }
        __builtin_amdgcn_sched_barrier(0);   // keep ds_write before ds_read (same wave, in-order LDS)
        float2 hv = *(const float2*)&scr[w][col][2*quad];
        #pragma unroll
        for (int i = 0; i < 2; ++i){
            int v  = 2*quad + i;
            int nt = v >> 2, r = v & 3;
            float h  = tanh_b(i == 0 ? hv.x : hv.y);
            u16 hi   = f2bf(h);
            u16 lo   = f2bf(h - bf2f(hi));
            int n    = w*32 + nt*16 + col;
            hhi[wb][r][n] = hi;
            hlo[wb][r][n] = lo;
            HC[(size_t)(t*B_ + bb0 + r)*D2_ + n] = hi;
        }
        __syncthreads();   // h_t (wb) visible before next step reads it
    }
}

// ---------------------------------------------------------------------------
// Generic MFMA GEMM: out[M=32768, N] = A[M,K](bf16, lda) @ W[K,N](fp32->bf16)
// mode 0: out bf16 row-major.
// mode 1: out fp32, +bias, row m=t*64+b remapped to out[(b*512+t)*V + n].
// mode 2: out bf16 = exp(2*acc)  (for EP/EQ).
// ---------------------------------------------------------------------------
__global__ __launch_bounds__(256) void k_gemm(const u16* __restrict__ A, int lda,
                                              const float* __restrict__ W,
                                              const float* __restrict__ bias,
                                              void* __restrict__ out,
                                              int K, int N, int mode){
    __shared__ u16 As[64][72];
    __shared__ u16 Ws[64][72];
    int tid  = threadIdx.x;
    int lane = tid & 63;
    int w    = tid >> 6;
    int col  = lane & 15;
    int quad = lane >> 4;
    int m0   = blockIdx.x * 64;
    int n0   = blockIdx.y * 64;

    f32x4 acc[4];
    #pragma unroll
    for (int nt = 0; nt < 4; ++nt)
        #pragma unroll
        for (int r = 0; r < 4; ++r) acc[nt][r] = 0.0f;

    for (int kk = 0; kk < K; kk += 64){
        #pragma unroll
        for (int i = 0; i < 8; ++i){
            int idx = tid + i*256;
            int r   = idx >> 5;
            int c2  = (idx & 31) * 2;
            u16x2 v2 = *(const u16x2*)&A[(size_t)(m0 + r)*lda + kk + c2];
            *(u16x2*)&As[r][c2] = v2;
        }
        #pragma unroll
        for (int i = 0; i < 16; ++i){
            int idx = tid + i*256;
            int k   = idx >> 6;
            int n   = idx & 63;
            Ws[n][k] = f2bf(W[(size_t)(kk + k)*N + n0 + n]);
        }
        __syncthreads();
        #pragma unroll
        for (int ks = 0; ks < 2; ++ks){
            s16x8 a = *(const s16x8*)&As[w*16 + col][ks*32 + quad*8];
            #pragma unroll
            for (int nt = 0; nt < 4; ++nt){
                s16x8 b = *(const s16x8*)&Ws[nt*16 + col][ks*32 + quad*8];
                acc[nt] = __builtin_amdgcn_mfma_f32_16x16x32_bf16(a, b, acc[nt], 0, 0, 0);
            }
        }
        __syncthreads();
    }
    #pragma unroll
    for (int nt = 0; nt < 4; ++nt){
        int n = n0 + nt*16 + col;
        float bv = (mode == 1 && bias) ? bias[n] : 0.0f;
        #pragma unroll
        for (int r = 0; r < 4; ++r){
            int m = m0 + w*16 + quad*4 + r;
            float v = acc[nt][r] + bv;
            if (mode == 1){
                int b = m & 63, t = m >> 6;
                ((float*)out)[(size_t)(b*T_ + t)*V_ + n] = v;
            } else if (mode == 2){
                ((u16*)out)[(size_t)m*N + n] = f2bf(__expf(2.0f * v));
            } else {
                ((u16*)out)[(size_t)m*N + n] = f2bf(v);
            }
        }
    }
}

// ---------------------------------------------------------------------------
// K5: energies. Block = (b, tt, pt), pt <= tt, 32x32 (t,t') tile over d=256.
// tanh(p+q) = 1 - 2/(1 + e^{2p} e^{2q}); grouped 4-per-rcp:
//   sum_i v_i/d_i = (sum_i v_i * prod_{j!=i} d_j) / prod_j d_j  -> 1 rcp / 4 d.
// ---------------------------------------------------------------------------
__global__ __launch_bounds__(256) void k_energy(const u16* __restrict__ EP,
                                                const u16* __restrict__ EQ,
                                                const float* __restrict__ v_attn,
                                                u16* __restrict__ Wx,
                                                float* __restrict__ l){
    __shared__ float eps[32][288];
    int tid = threadIdx.x;
    int blk = blockIdx.x;
    int b   = blk / 136;
    int pi  = blk % 136;
    int tt  = 0;
    while ((tt+1)*(tt+2)/2 <= pi) ++tt;
    int pt  = pi - tt*(tt+1)/2;

    int t_l = tid >> 3;
    int dg  = tid & 7;
    int d0  = dg * 32;
    int t   = tt*32 + t_l;

    // stage EP rows [pt*32, pt*32+32) as fp32 into padded layout
    #pragma unroll
    for (int i = 0; i < 8; ++i){
        int idx = tid + i*256;            // 0..2047, 4 bf16 each
        int row = idx >> 6;
        int c4  = (idx & 63) * 4;
        int pc  = c4 + ((c4 >> 5) << 2);  // +4 dwords per 32-chunk
        u16x4 v4 = *(const u16x4*)&EP[((size_t)((pt*32 + row)*B_ + b))*D_ + c4];
        float4 f4 = make_float4(bf2f(v4.x), bf2f(v4.y), bf2f(v4.z), bf2f(v4.w));
        *(float4*)&eps[row][pc] = f4;
    }

    float eq[32], vm2[32], sv = 0.0f;
    #pragma unroll
    for (int i = 0; i < 8; ++i){
        u16x4 v4 = *(const u16x4*)&EQ[((size_t)(t*B_ + b))*D_ + d0 + i*4];
        eq[i*4+0] = bf2f(v4.x); eq[i*4+1] = bf2f(v4.y);
        eq[i*4+2] = bf2f(v4.z); eq[i*4+3] = bf2f(v4.w);
    }
    #pragma unroll
    for (int i = 0; i < 32; ++i){
        float v = v_attn[d0 + i];
        sv += v;
        vm2[i] = -2.0f * v;
    }
    __syncthreads();

    float lsum = 0.0f;
    for (int tpl = 0; tpl < 32; ++tpl){
        int tp = pt*32 + tpl;
        float acc = sv;
        #pragma unroll
        for (int g = 0; g < 8; ++g){
            float4 ep = *(const float4*)&eps[tpl][dg*36 + 4*g];
            float da = fmaf(ep.x, eq[4*g+0], 1.0f);
            float db = fmaf(ep.y, eq[4*g+1], 1.0f);
            float dc = fmaf(ep.z, eq[4*g+2], 1.0f);
            float dd = fmaf(ep.w, eq[4*g+3], 1.0f);
            float dab = da * db;
            float dcd = dc * dd;
            float nab = fmaf(vm2[4*g+1], da, vm2[4*g+0] * db);
            float ncd = fmaf(vm2[4*g+3], dc, vm2[4*g+2] * dd);
            float num = fmaf(ncd, dab, nab * dcd);
            acc = fmaf(num, __builtin_amdgcn_rcpf(dab * dcd), acc);
        }
        acc += __shfl_xor(acc, 1);
        acc += __shfl_xor(acc, 2);
        acc += __shfl_xor(acc, 4);
        float pe = __expf(acc);
        if (dg == 0 && tp < t){
            u16 peb = f2bf(pe);
            Wx[((size_t)(b*T_ + t))*T_ + tp] = peb;
            lsum += bf2f(peb);
        }
    }
    if (dg == 0 && lsum != 0.0f) atomicAdd(&l[b*T_ + t], lsum);
}

// ---------------------------------------------------------------------------
// K6: ctx[b][t][d] = (sum_t' Wx[b][t][t'] * h[t'][d]) / l[b][t]; t=0 -> h[0].
// ---------------------------------------------------------------------------
__global__ __launch_bounds__(256) void k_ctx(const u16* __restrict__ Wx,
                                             u16* __restrict__ HC,
                                             const float* __restrict__ l){
    __shared__ u16 As[64][72];
    __shared__ u16 Ws[64][72];
    int tid  = threadIdx.x;
    int lane = tid & 63;
    int w    = tid >> 6;
    int col  = lane & 15;
    int quad = lane >> 4;
    int b    = blockIdx.y;
    int m0   = (blockIdx.x >> 2) * 64;   // t tile
    int n0   = (blockIdx.x & 3) * 64;    // d tile

    const u16* A = Wx + (size_t)b * T_ * T_;

    f32x4 acc[4];
    #pragma unroll
    for (int nt = 0; nt < 4; ++nt)
        #pragma unroll
        for (int r = 0; r < 4; ++r) acc[nt][r] = 0.0f;

    for (int kk = 0; kk < T_; kk += 64){
        #pragma unroll
        for (int i = 0; i < 8; ++i){
            int idx = tid + i*256;
            int r   = idx >> 5;
            int c2  = (idx & 31) * 2;
            u16x2 v2 = *(const u16x2*)&A[(size_t)(m0 + r)*T_ + kk + c2];
            *(u16x2*)&As[r][c2] = v2;
        }
        #pragma unroll
        for (int i = 0; i < 8; ++i){
            int idx = tid + i*256;
            int k   = idx >> 5;
            int n2  = (idx & 31) * 2;
            u16x2 v2 = *(const u16x2*)&HC[((size_t)((kk + k)*B_ + b))*D2_ + n0 + n2];
            Ws[n2][k]   = v2.x;
            Ws[n2+1][k] = v2.y;
        }
        __syncthreads();
        #pragma unroll
        for (int ks = 0; ks < 2; ++ks){
            s16x8 a = *(const s16x8*)&As[w*16 + col][ks*32 + quad*8];
            #pragma unroll
            for (int nt = 0; nt < 4; ++nt){
                s16x8 bb = *(const s16x8*)&Ws[nt*16 + col][ks*32 + quad*8];
                acc[nt] = __builtin_amdgcn_mfma_f32_16x16x32_bf16(a, bb, acc[nt], 0, 0, 0);
            }
        }
        __syncthreads();
    }

    float linv[4];
    #pragma unroll
    for (int r = 0; r < 4; ++r){
        int t = m0 + w*16 + quad*4 + r;
        float lv = (t > 0) ? l[b*T_ + t] : 1.0f;
        linv[r] = 1.0f / lv;
    }
    #pragma unroll
    for (int nt = 0; nt < 4; ++nt){
        int n = n0 + nt*16 + col;
        #pragma unroll
        for (int r = 0; r < 4; ++r){
            int t = m0 + w*16 + quad*4 + r;
            u16 ov;
            if (t == 0) ov = HC[(size_t)b*D2_ + n];          // ctx(0) = h(0)
            else        ov = f2bf(acc[nt][r] * linv[r]);
            HC[((size_t)(t*B_ + b))*D2_ + D_ + n] = ov;
        }
    }
}

// ---------------------------------------------------------------------------
extern "C" void kernel_launch(void* const* d_in, const int* in_sizes, int n_in,
                              void* d_out, int out_size, void* d_ws, size_t ws_size,
                              hipStream_t stream){
    const int*   x     = (const int*)d_in[0];
    const float* embed = (const float*)d_in[1];
    const float* W_ih  = (const float*)d_in[2];
    const float* W_hh  = (const float*)d_in[3];
    const float* b_h   = (const float*)d_in[4];
    const float* W_att = (const float*)d_in[5];
    const float* U_att = (const float*)d_in[6];
    const float* v_att = (const float*)d_in[7];
    const float* fc_W  = (const float*)d_in[8];
    const float* fc_b  = (const float*)d_in[9];

    char* ws = (char*)d_ws;
    float* EW = (float*)ws;                         // 0.5 MB
    u16*   HC = (u16*)(ws + 524288);                // 32 MB  [h|ctx] bf16
    u16*   EP = (u16*)(ws + 34078720);              // 16 MB  exp(2*P) bf16
    u16*   EQ = (u16*)(ws + 50855936);              // 16 MB  exp(2*Q) bf16
    float* l  = (float*)(ws + 67633152);            // 128 KB row sums
    u16*   Wx = (u16*)d_out;                        // 33.5 MB scratch in d_out (dead until fc)

    hipMemsetAsync(d_out, 0, (size_t)B_*T_*T_*2, stream);   // zero Wx (upper triangle stays 0)
    hipMemsetAsync(l, 0, B_*T_*4, stream);

    k_ew    <<<dim3(V_),       dim3(256), 0, stream>>>(embed, W_ih, b_h, EW);
    k_rnn   <<<dim3(16),       dim3(512), 0, stream>>>(x, EW, W_hh, HC);
    k_gemm  <<<dim3(512, 4),   dim3(256), 0, stream>>>(HC, D2_, W_att, nullptr, (void*)EP, D_, D_, 2);
    k_gemm  <<<dim3(512, 4),   dim3(256), 0, stream>>>(HC, D2_, U_att, nullptr, (void*)EQ, D_, D_, 2);
    k_energy<<<dim3(B_*136),   dim3(256), 0, stream>>>(EP, EQ, v_att, Wx, l);
    k_ctx   <<<dim3(32, B_),   dim3(256), 0, stream>>>(Wx, HC, l);
    k_gemm  <<<dim3(512, 8),   dim3(256), 0, stream>>>(HC, D2_, fc_W, fc_b, d_out, D2_, V_, 1);
}

// Round 6
// 1184.085 us; speedup vs baseline: 2.5971x; 1.0907x over previous
//
#include <hip/hip_runtime.h>
#include <hip/hip_bf16.h>

#define B_  64
#define T_  512
#define V_  512
#define E_  128
#define D_  256
#define D2_ 512

typedef unsigned short u16;
typedef unsigned int   u32;
typedef short s16x8 __attribute__((ext_vector_type(8)));
typedef float f32x4 __attribute__((ext_vector_type(4)));
typedef unsigned short u16x2 __attribute__((ext_vector_type(2)));
typedef unsigned short u16x4 __attribute__((ext_vector_type(4)));

__device__ __forceinline__ float bf2f(u16 u){
    union { u32 i; float f; } c; c.i = ((u32)u) << 16; return c.f;
}
__device__ __forceinline__ u16 f2bf(float f){
    union { float f; u32 i; } c; c.f = f;
    u32 u = c.i;
    return (u16)((u + 0x7fffu + ((u >> 16) & 1u)) >> 16);
}
// tanh for bounded args (|x| <~ 20): 1 - 2/(e^{2x}+1).
__device__ __forceinline__ float tanh_b(float x){
    float e = __expf(2.0f * x);
    return fmaf(-2.0f, __builtin_amdgcn_rcpf(e + 1.0f), 1.0f);
}
// Workgroup barrier that only drains LDS (lgkm) — leaves global loads/stores
// in flight. Safe when cross-wave communication is LDS-only.
__device__ __forceinline__ void barrier_lgkm(){
    asm volatile("s_waitcnt lgkmcnt(0)\n\ts_barrier" ::: "memory");
}

// ---------------------------------------------------------------------------
// K1: EW[v,d] = sum_e embed[v,e] * W_ih[e,d] + b_h[d]   (512 x 256, fp32 exact)
// ---------------------------------------------------------------------------
__global__ __launch_bounds__(256) void k_ew(const float* __restrict__ embed,
                                            const float* __restrict__ W_ih,
                                            const float* __restrict__ b_h,
                                            float* __restrict__ EW){
    __shared__ float er[E_];
    int v = blockIdx.x;
    int tid = threadIdx.x;
    if (tid < E_) er[tid] = embed[v*E_ + tid];
    __syncthreads();
    float acc = b_h[tid];
    #pragma unroll 4
    for (int e = 0; e < E_; ++e) acc += er[e] * W_ih[e*D_ + tid];
    EW[v*D_ + tid] = acc;
}

// ---------------------------------------------------------------------------
// K1b: XP[t*64+b][d] = EW[x[b][t]][d]  (fp32, 32 MB; aliases EP/EQ region)
// ---------------------------------------------------------------------------
__global__ __launch_bounds__(256) void k_gather(const int* __restrict__ x,
                                                const float* __restrict__ EW,
                                                float* __restrict__ XP){
    int m = blockIdx.x * 4 + (threadIdx.x >> 6);   // row index t*64+b
    int lane = threadIdx.x & 63;
    int b = m & 63, t = m >> 6;
    int v = x[b*T_ + t];
    float4 val = *(const float4*)&EW[v*D_ + lane*4];
    *(float4*)&XP[(size_t)m*D_ + lane*4] = val;
}

// ---------------------------------------------------------------------------
// K2: sequential h-chain. 16 blocks x 4 batches (M=4), 512 threads (8 waves).
// h kept as bf16 hi+lo (2 MFMA passes). Raw lgkm-only barrier per step keeps
// HC stores + XP prefetch loads in flight across the step boundary.
// ---------------------------------------------------------------------------
__global__ __launch_bounds__(512, 2) void k_rnn(const float* __restrict__ XP,
                                                const float* __restrict__ W_hh,
                                                u16* __restrict__ HC){
    __shared__ u16 hhi[2][4][272];
    __shared__ u16 hlo[2][4][272];
    __shared__ float scr[8][16][10];   // [wave][col][v(8)+pad2]
    int tid  = threadIdx.x;
    int lane = tid & 63;
    int w    = tid >> 6;          // wave 0..7: n-range w*32..w*32+31
    int col  = lane & 15;
    int colA = col & 3;           // A-row alias (rows 4..15 duplicate 0..3)
    int quad = lane >> 4;
    int bb0  = blockIdx.x * 4;

    // Preload W_hh B-fragments: k = ks*32+quad*8+j, n = w*32+nt*16+col
    s16x8 bfh[2][8];
    #pragma unroll
    for (int nt = 0; nt < 2; ++nt){
        int n = w*32 + nt*16 + col;
        #pragma unroll
        for (int ks = 0; ks < 8; ++ks){
            s16x8 th;
            #pragma unroll
            for (int j = 0; j < 8; ++j){
                int k = ks*32 + quad*8 + j;
                th[j] = (short)f2bf(W_hh[k*D_ + n]);
            }
            bfh[nt][ks] = th;
        }
    }
    for (int i = tid; i < 2*4*272; i += 512){
        (&hhi[0][0][0])[i] = 0; (&hlo[0][0][0])[i] = 0;
    }

    // stepped base pointers (advance by one t-slab per step)
    const float* p  = XP + (size_t)bb0*D_ + w*32 + col;       // + r*D_ + nt*16
    u16*         hc = HC + (size_t)bb0*D2_ + w*32 + col;      // + r*D2_ + nt*16

    float ewv[2][4] = {{0,0,0,0},{0,0,0,0}};
    if (quad == 0){   // prefetch xp for t=0
        #pragma unroll
        for (int nt = 0; nt < 2; ++nt)
            #pragma unroll
            for (int r = 0; r < 4; ++r)
                ewv[nt][r] = p[r*D_ + nt*16];
    }
    p += (size_t)B_*D_;
    __syncthreads();

    for (int t = 0; t < T_; ++t){
        int rb = t & 1, wb = rb ^ 1;
        f32x4 accH[2], accL[2];
        #pragma unroll
        for (int nt = 0; nt < 2; ++nt)
            #pragma unroll
            for (int r = 0; r < 4; ++r){ accH[nt][r] = ewv[nt][r]; accL[nt][r] = 0.0f; }

        // prefetch next step's xp (stays in flight across raw barrier)
        if (quad == 0 && t + 1 < T_){
            #pragma unroll
            for (int nt = 0; nt < 2; ++nt)
                #pragma unroll
                for (int r = 0; r < 4; ++r)
                    ewv[nt][r] = p[r*D_ + nt*16];
        }
        p += (size_t)B_*D_;

        #pragma unroll
        for (int ks = 0; ks < 8; ++ks){
            s16x8 a_hi = *(const s16x8*)&hhi[rb][colA][ks*32 + quad*8];
            s16x8 a_lo = *(const s16x8*)&hlo[rb][colA][ks*32 + quad*8];
            #pragma unroll
            for (int nt = 0; nt < 2; ++nt){
                accH[nt] = __builtin_amdgcn_mfma_f32_16x16x32_bf16(a_hi, bfh[nt][ks], accH[nt], 0, 0, 0);
                accL[nt] = __builtin_amdgcn_mfma_f32_16x16x32_bf16(a_lo, bfh[nt][ks], accL[nt], 0, 0, 0);
            }
        }

        // repack: quad0's 8 C-values -> per-wave scratch -> 2 per lane full-wave
        if (quad == 0){
            f32x4 v0, v1;
            #pragma unroll
            for (int r = 0; r < 4; ++r){ v0[r] = accH[0][r] + accL[0][r]; v1[r] = accH[1][r] + accL[1][r]; }
            *(f32x4*)&scr[w][col][0] = v0;   // v = nt*4+r : 0..3
            *(f32x4*)&scr[w][col][4] = v1;   // 4..7
        }
        float2 hv = *(const float2*)&scr[w][col][2*quad];
        #pragma unroll
        for (int i = 0; i < 2; ++i){
            int v  = 2*quad + i;
            int nt = v >> 2, r = v & 3;
            float h  = tanh_b(i == 0 ? hv.x : hv.y);
            u16 hi   = f2bf(h);
            u16 lo   = f2bf(h - bf2f(hi));
            int n    = w*32 + nt*16 + col;
            hhi[wb][r][n] = hi;
            hlo[wb][r][n] = lo;
            hc[r*D2_ + nt*16] = hi;
        }
        hc += (size_t)B_*D2_;
        barrier_lgkm();   // h_t LDS visible; HC stores/XP loads stay in flight
    }
}

// ---------------------------------------------------------------------------
// Generic MFMA GEMM: out[M=32768, N] = A[M,K](bf16, lda) @ W[K,N](fp32->bf16)
// mode 0: out bf16 row-major.
// mode 1: out fp32, +bias, row m=t*64+b remapped to out[(b*512+t)*V + n].
// mode 2: out bf16 = exp(2*acc)  (for EP/EQ).
// ---------------------------------------------------------------------------
__global__ __launch_bounds__(256) void k_gemm(const u16* __restrict__ A, int lda,
                                              const float* __restrict__ W,
                                              const float* __restrict__ bias,
                                              void* __restrict__ out,
                                              int K, int N, int mode){
    __shared__ u16 As[64][72];
    __shared__ u16 Ws[64][72];
    int tid  = threadIdx.x;
    int lane = tid & 63;
    int w    = tid >> 6;
    int col  = lane & 15;
    int quad = lane >> 4;
    int m0   = blockIdx.x * 64;
    int n0   = blockIdx.y * 64;

    f32x4 acc[4];
    #pragma unroll
    for (int nt = 0; nt < 4; ++nt)
        #pragma unroll
        for (int r = 0; r < 4; ++r) acc[nt][r] = 0.0f;

    for (int kk = 0; kk < K; kk += 64){
        #pragma unroll
        for (int i = 0; i < 8; ++i){
            int idx = tid + i*256;
            int r   = idx >> 5;
            int c2  = (idx & 31) * 2;
            u16x2 v2 = *(const u16x2*)&A[(size_t)(m0 + r)*lda + kk + c2];
            *(u16x2*)&As[r][c2] = v2;
        }
        #pragma unroll
        for (int i = 0; i < 16; ++i){
            int idx = tid + i*256;
            int k   = idx >> 6;
            int n   = idx & 63;
            Ws[n][k] = f2bf(W[(size_t)(kk + k)*N + n0 + n]);
        }
        barrier_lgkm();
        #pragma unroll
        for (int ks = 0; ks < 2; ++ks){
            s16x8 a = *(const s16x8*)&As[w*16 + col][ks*32 + quad*8];
            #pragma unroll
            for (int nt = 0; nt < 4; ++nt){
                s16x8 b = *(const s16x8*)&Ws[nt*16 + col][ks*32 + quad*8];
                acc[nt] = __builtin_amdgcn_mfma_f32_16x16x32_bf16(a, b, acc[nt], 0, 0, 0);
            }
        }
        barrier_lgkm();
    }
    #pragma unroll
    for (int nt = 0; nt < 4; ++nt){
        int n = n0 + nt*16 + col;
        float bv = (mode == 1 && bias) ? bias[n] : 0.0f;
        #pragma unroll
        for (int r = 0; r < 4; ++r){
            int m = m0 + w*16 + quad*4 + r;
            float v = acc[nt][r] + bv;
            if (mode == 1){
                int b = m & 63, t = m >> 6;
                ((float*)out)[(size_t)(b*T_ + t)*V_ + n] = v;
            } else if (mode == 2){
                ((u16*)out)[(size_t)m*N + n] = f2bf(__expf(2.0f * v));
            } else {
                ((u16*)out)[(size_t)m*N + n] = f2bf(v);
            }
        }
    }
}

// ---------------------------------------------------------------------------
// K5: energies. Block = (b, tt, pt), pt <= tt, 32x32 (t,t') tile over d=256.
// tanh(p+q) = 1 - 2/(1 + e^{2p} e^{2q}); grouped 4-per-rcp.
// ---------------------------------------------------------------------------
__global__ __launch_bounds__(256) void k_energy(const u16* __restrict__ EP,
                                                const u16* __restrict__ EQ,
                                                const float* __restrict__ v_attn,
                                                u16* __restrict__ Wx,
                                                float* __restrict__ l){
    __shared__ float eps[32][288];
    int tid = threadIdx.x;
    int blk = blockIdx.x;
    int b   = blk / 136;
    int pi  = blk % 136;
    int tt  = 0;
    while ((tt+1)*(tt+2)/2 <= pi) ++tt;
    int pt  = pi - tt*(tt+1)/2;

    int t_l = tid >> 3;
    int dg  = tid & 7;
    int d0  = dg * 32;
    int t   = tt*32 + t_l;

    // stage EP rows [pt*32, pt*32+32) as fp32 into padded layout
    #pragma unroll
    for (int i = 0; i < 8; ++i){
        int idx = tid + i*256;            // 0..2047, 4 bf16 each
        int row = idx >> 6;
        int c4  = (idx & 63) * 4;
        int pc  = c4 + ((c4 >> 5) << 2);  // +4 dwords per 32-chunk
        u16x4 v4 = *(const u16x4*)&EP[((size_t)((pt*32 + row)*B_ + b))*D_ + c4];
        float4 f4 = make_float4(bf2f(v4.x), bf2f(v4.y), bf2f(v4.z), bf2f(v4.w));
        *(float4*)&eps[row][pc] = f4;
    }

    float eq[32], vm2[32], sv = 0.0f;
    #pragma unroll
    for (int i = 0; i < 8; ++i){
        u16x4 v4 = *(const u16x4*)&EQ[((size_t)(t*B_ + b))*D_ + d0 + i*4];
        eq[i*4+0] = bf2f(v4.x); eq[i*4+1] = bf2f(v4.y);
        eq[i*4+2] = bf2f(v4.z); eq[i*4+3] = bf2f(v4.w);
    }
    #pragma unroll
    for (int i = 0; i < 32; ++i){
        float v = v_attn[d0 + i];
        sv += v;
        vm2[i] = -2.0f * v;
    }
    barrier_lgkm();

    float lsum = 0.0f;
    for (int tpl = 0; tpl < 32; ++tpl){
        int tp = pt*32 + tpl;
        float acc = sv;
        #pragma unroll
        for (int g = 0; g < 8; ++g){
            float4 ep = *(const float4*)&eps[tpl][dg*36 + 4*g];
            float da = fmaf(ep.x, eq[4*g+0], 1.0f);
            float db = fmaf(ep.y, eq[4*g+1], 1.0f);
            float dc = fmaf(ep.z, eq[4*g+2], 1.0f);
            float dd = fmaf(ep.w, eq[4*g+3], 1.0f);
            float dab = da * db;
            float dcd = dc * dd;
            float nab = fmaf(vm2[4*g+1], da, vm2[4*g+0] * db);
            float ncd = fmaf(vm2[4*g+3], dc, vm2[4*g+2] * dd);
            float num = fmaf(ncd, dab, nab * dcd);
            acc = fmaf(num, __builtin_amdgcn_rcpf(dab * dcd), acc);
        }
        acc += __shfl_xor(acc, 1);
        acc += __shfl_xor(acc, 2);
        acc += __shfl_xor(acc, 4);
        float pe = __expf(acc);
        if (dg == 0 && tp < t){
            u16 peb = f2bf(pe);
            Wx[((size_t)(b*T_ + t))*T_ + tp] = peb;
            lsum += bf2f(peb);
        }
    }
    if (dg == 0 && lsum != 0.0f) atomicAdd(&l[b*T_ + t], lsum);
}

// ---------------------------------------------------------------------------
// K6: ctx[b][t][d] = (sum_t' Wx[b][t][t'] * h[t'][d]) / l[b][t]; t=0 -> h[0].
// ---------------------------------------------------------------------------
__global__ __launch_bounds__(256) void k_ctx(const u16* __restrict__ Wx,
                                             u16* __restrict__ HC,
                                             const float* __restrict__ l){
    __shared__ u16 As[64][72];
    __shared__ u16 Ws[64][72];
    int tid  = threadIdx.x;
    int lane = tid & 63;
    int w    = tid >> 6;
    int col  = lane & 15;
    int quad = lane >> 4;
    int b    = blockIdx.y;
    int m0   = (blockIdx.x >> 2) * 64;   // t tile
    int n0   = (blockIdx.x & 3) * 64;    // d tile

    const u16* A = Wx + (size_t)b * T_ * T_;

    f32x4 acc[4];
    #pragma unroll
    for (int nt = 0; nt < 4; ++nt)
        #pragma unroll
        for (int r = 0; r < 4; ++r) acc[nt][r] = 0.0f;

    for (int kk = 0; kk < T_; kk += 64){
        #pragma unroll
        for (int i = 0; i < 8; ++i){
            int idx = tid + i*256;
            int r   = idx >> 5;
            int c2  = (idx & 31) * 2;
            u16x2 v2 = *(const u16x2*)&A[(size_t)(m0 + r)*T_ + kk + c2];
            *(u16x2*)&As[r][c2] = v2;
        }
        #pragma unroll
        for (int i = 0; i < 8; ++i){
            int idx = tid + i*256;
            int k   = idx >> 5;
            int n2  = (idx & 31) * 2;
            u16x2 v2 = *(const u16x2*)&HC[((size_t)((kk + k)*B_ + b))*D2_ + n0 + n2];
            Ws[n2][k]   = v2.x;
            Ws[n2+1][k] = v2.y;
        }
        barrier_lgkm();
        #pragma unroll
        for (int ks = 0; ks < 2; ++ks){
            s16x8 a = *(const s16x8*)&As[w*16 + col][ks*32 + quad*8];
            #pragma unroll
            for (int nt = 0; nt < 4; ++nt){
                s16x8 bb = *(const s16x8*)&Ws[nt*16 + col][ks*32 + quad*8];
                acc[nt] = __builtin_amdgcn_mfma_f32_16x16x32_bf16(a, bb, acc[nt], 0, 0, 0);
            }
        }
        barrier_lgkm();
    }

    float linv[4];
    #pragma unroll
    for (int r = 0; r < 4; ++r){
        int t = m0 + w*16 + quad*4 + r;
        float lv = (t > 0) ? l[b*T_ + t] : 1.0f;
        linv[r] = 1.0f / lv;
    }
    #pragma unroll
    for (int nt = 0; nt < 4; ++nt){
        int n = n0 + nt*16 + col;
        #pragma unroll
        for (int r = 0; r < 4; ++r){
            int t = m0 + w*16 + quad*4 + r;
            u16 ov;
            if (t == 0) ov = HC[(size_t)b*D2_ + n];          // ctx(0) = h(0)
            else        ov = f2bf(acc[nt][r] * linv[r]);
            HC[((size_t)(t*B_ + b))*D2_ + D_ + n] = ov;
        }
    }
}

// ---------------------------------------------------------------------------
extern "C" void kernel_launch(void* const* d_in, const int* in_sizes, int n_in,
                              void* d_out, int out_size, void* d_ws, size_t ws_size,
                              hipStream_t stream){
    const int*   x     = (const int*)d_in[0];
    const float* embed = (const float*)d_in[1];
    const float* W_ih  = (const float*)d_in[2];
    const float* W_hh  = (const float*)d_in[3];
    const float* b_h   = (const float*)d_in[4];
    const float* W_att = (const float*)d_in[5];
    const float* U_att = (const float*)d_in[6];
    const float* v_att = (const float*)d_in[7];
    const float* fc_W  = (const float*)d_in[8];
    const float* fc_b  = (const float*)d_in[9];

    char* ws = (char*)d_ws;
    float* EW = (float*)ws;                         // 0.5 MB
    u16*   HC = (u16*)(ws + 524288);                // 32 MB  [h|ctx] bf16
    u16*   EP = (u16*)(ws + 34078720);              // 16 MB  exp(2*P) bf16
    u16*   EQ = (u16*)(ws + 50855936);              // 16 MB  exp(2*Q) bf16
    float* XP = (float*)(ws + 34078720);            // 32 MB  fp32, ALIASES EP+EQ (dead after k_rnn)
    float* l  = (float*)(ws + 67633152);            // 128 KB row sums
    u16*   Wx = (u16*)d_out;                        // 33.5 MB scratch in d_out (dead until fc)

    hipMemsetAsync(d_out, 0, (size_t)B_*T_*T_*2, stream);   // zero Wx (upper triangle stays 0)
    hipMemsetAsync(l, 0, B_*T_*4, stream);

    k_ew    <<<dim3(V_),        dim3(256), 0, stream>>>(embed, W_ih, b_h, EW);
    k_gather<<<dim3(T_*B_/4),   dim3(256), 0, stream>>>(x, EW, XP);
    k_rnn   <<<dim3(16),        dim3(512), 0, stream>>>(XP, W_hh, HC);
    k_gemm  <<<dim3(512, 4),    dim3(256), 0, stream>>>(HC, D2_, W_att, nullptr, (void*)EP, D_, D_, 2);
    k_gemm  <<<dim3(512, 4),    dim3(256), 0, stream>>>(HC, D2_, U_att, nullptr, (void*)EQ, D_, D_, 2);
    k_energy<<<dim3(B_*136),    dim3(256), 0, stream>>>(EP, EQ, v_att, Wx, l);
    k_ctx   <<<dim3(32, B_),    dim3(256), 0, stream>>>(Wx, HC, l);
    k_gemm  <<<dim3(512, 8),    dim3(256), 0, stream>>>(HC, D2_, fc_W, fc_b, d_out, D2_, V_, 1);
}